// Round 1
// baseline (2264.772 us; speedup 1.0000x reference)
//
#include <hip/hip_runtime.h>
#include <hip/hip_fp16.h>

typedef unsigned int u32;
typedef _Float16 h2v __attribute__((ext_vector_type(2)));

#define B_ 64
#define T_ 1024
#define H_ 512
#define I_ 512

// ---------------- fp16 dot2 helper (v_dot2_f32_f16) ----------------
__device__ __forceinline__ float dot2f(u32 w, u32 h, float acc) {
#if __has_builtin(__builtin_amdgcn_fdot2)
    return __builtin_amdgcn_fdot2(__builtin_bit_cast(h2v, w),
                                  __builtin_bit_cast(h2v, h), acc, false);
#else
    __half2 a = __builtin_bit_cast(__half2, w);
    __half2 b = __builtin_bit_cast(__half2, h);
    return acc + __low2float(a) * __low2float(b) + __high2float(a) * __high2float(b);
#endif
}

// ---------------- W_hh repack: fp32 -> per-thread fp16 layout ----------------
// Thread tid (0..511) of the scan kernel: g = tid>>3 owns outputs j = g*8+o (o=0..7),
// sub = tid&7 owns i-slice [sub*64, sub*64+64).
// o=0..5 -> VGPR block wreg[r][tid], r = o*32+k (k = half2 index within slice)
// o=6..7 -> LDS block wlds[c][tid][q], c = (o-6)*8 + chunk, covering half2 kk=(c&7)*4+q
__global__ void prep_w(const float* __restrict__ Whh, u32* __restrict__ wreg,
                       u32* __restrict__ wlds) {
    const int tid = threadIdx.x;
    const int g = tid >> 3, sub = tid & 7;
    const int bid = blockIdx.x;
    if (bid < 192) {
        const int r = bid, o = r >> 5, k = r & 31;
        const int j = g * 8 + o, i = sub * 64 + 2 * k;
        __half2 p = __halves2half2(__float2half(Whh[j * H_ + i]),
                                   __float2half(Whh[j * H_ + i + 1]));
        wreg[r * 512 + tid] = __builtin_bit_cast(u32, p);
    } else {
        const int c = bid - 192;            // 0..15
        const int o = 6 + (c >> 3);
        const int j = g * 8 + o;
        for (int q = 0; q < 4; q++) {
            const int kk = (c & 7) * 4 + q;
            const int i = sub * 64 + 2 * kk;
            __half2 p = __halves2half2(__float2half(Whh[j * H_ + i]),
                                       __float2half(Whh[j * H_ + i + 1]));
            wlds[c * 2048 + tid * 4 + q] = __builtin_bit_cast(u32, p);
        }
    }
}

// ---------------- Phase 1: Xp = X @ W_ih^T + (b_ih + b_hh), into d_out ----------------
#define BM 128
#define BN 64
#define BK 32

__launch_bounds__(256, 3)
__global__ void gemm_xp(const float* __restrict__ X, const float* __restrict__ Wih,
                        const float* __restrict__ bih, const float* __restrict__ bhh,
                        float* __restrict__ out) {
    __shared__ float Xs[BK][BM + 4];
    __shared__ float Ws[BK][BN + 4];
    const int t = threadIdx.x;
    const int bn = blockIdx.x & 7;       // 512/64 = 8 tiles
    const int bm = blockIdx.x >> 3;      // 65536/128 = 512 tiles
    const int m0 = bm * BM, n0 = bn * BN;
    const int tm = t & 15, tn = t >> 4;  // 16 x 16 thread grid, 8x4 per thread
    float acc[8][4];
#pragma unroll
    for (int i = 0; i < 8; i++)
#pragma unroll
        for (int j = 0; j < 4; j++) acc[i][j] = 0.f;
    const int kc = t & 7, rr = t >> 3;
    for (int kt = 0; kt < I_ / BK; kt++) {
        const int k0 = kt * BK;
#pragma unroll
        for (int it = 0; it < 4; it++) {
            const int m = it * 32 + rr;
            float4 v = *(const float4*)&X[(size_t)(m0 + m) * I_ + k0 + kc * 4];
            Xs[kc * 4 + 0][m] = v.x; Xs[kc * 4 + 1][m] = v.y;
            Xs[kc * 4 + 2][m] = v.z; Xs[kc * 4 + 3][m] = v.w;
        }
#pragma unroll
        for (int it = 0; it < 2; it++) {
            const int n = it * 32 + rr;
            float4 v = *(const float4*)&Wih[(size_t)(n0 + n) * I_ + k0 + kc * 4];
            Ws[kc * 4 + 0][n] = v.x; Ws[kc * 4 + 1][n] = v.y;
            Ws[kc * 4 + 2][n] = v.z; Ws[kc * 4 + 3][n] = v.w;
        }
        __syncthreads();
#pragma unroll
        for (int k = 0; k < BK; k++) {
            float4 a0 = *(const float4*)&Xs[k][tm * 8];
            float4 a1 = *(const float4*)&Xs[k][tm * 8 + 4];
            float4 bv = *(const float4*)&Ws[k][tn * 4];
            float a[8] = {a0.x, a0.y, a0.z, a0.w, a1.x, a1.y, a1.z, a1.w};
            float bb[4] = {bv.x, bv.y, bv.z, bv.w};
#pragma unroll
            for (int mi = 0; mi < 8; mi++)
#pragma unroll
                for (int ni = 0; ni < 4; ni++)
                    acc[mi][ni] = fmaf(a[mi], bb[ni], acc[mi][ni]);
        }
        __syncthreads();
    }
    float4 b1 = *(const float4*)&bih[n0 + tn * 4];
    float4 b2 = *(const float4*)&bhh[n0 + tn * 4];
    float4 bs = {b1.x + b2.x, b1.y + b2.y, b1.z + b2.z, b1.w + b2.w};
#pragma unroll
    for (int mi = 0; mi < 8; mi++) {
        const int row = m0 + tm * 8 + mi;
        float4 st = {acc[mi][0] + bs.x, acc[mi][1] + bs.y,
                     acc[mi][2] + bs.z, acc[mi][3] + bs.w};
        *(float4*)&out[(size_t)row * H_ + n0 + tn * 4] = st;
    }
}

// ---------------- Phase 2: sequential scan, one block per batch element ----------------
// 512 threads. W_hh (fp16): 192 half2/thread in VGPRs + 64 half2/thread in LDS (128KB).
// h broadcast via XOR-swizzled half2 LDS array, ping-pong buffers -> 1 barrier/step.
__launch_bounds__(512, 2)
__global__ void rnn_scan(const u32* __restrict__ wreg, const u32* __restrict__ wlds_g,
                         float* __restrict__ out) {
    __shared__ u32 wl[32768];   // 128 KB
    __shared__ u32 hh[512];     // 2 x 256 half2 (ping-pong)
    const int tid = threadIdx.x;
    const int sub = tid & 7;
    u32 w2[192];
#pragma unroll
    for (int r = 0; r < 192; r++) w2[r] = wreg[r * 512 + tid];
#pragma unroll
    for (int i = 0; i < 64; i++) wl[i * 512 + tid] = wlds_g[i * 512 + tid];
    hh[tid] = 0u;               // h0 = 0 (both buffers zeroed)
    __syncthreads();
    float* outb = out + (size_t)blockIdx.x * (T_ * H_);
    float xp = outb[tid];       // Xp[b,0,tid]
    const int xorkey = sub << 2;
    for (int t = 0; t < T_; t++) {
        const float xpn = (t + 1 < T_) ? outb[(size_t)(t + 1) * H_ + tid] : 0.f;
        const int rb = (t & 1) << 8;   // read buffer base (dwords)
        float acc[8] = {0, 0, 0, 0, 0, 0, 0, 0};
#pragma unroll
        for (int cc = 0; cc < 4; cc++) {
            uint4 hA = *(const uint4*)&hh[rb + ((sub * 32 + cc * 8) ^ xorkey)];
            uint4 hB = *(const uint4*)&hh[rb + ((sub * 32 + cc * 8 + 4) ^ xorkey)];
            uint4 w6a = *(const uint4*)&wl[(cc * 2 + 0) * 2048 + tid * 4];
            uint4 w6b = *(const uint4*)&wl[(cc * 2 + 1) * 2048 + tid * 4];
            uint4 w7a = *(const uint4*)&wl[(cc * 2 + 8) * 2048 + tid * 4];
            uint4 w7b = *(const uint4*)&wl[(cc * 2 + 9) * 2048 + tid * 4];
            u32 hc[8] = {hA.x, hA.y, hA.z, hA.w, hB.x, hB.y, hB.z, hB.w};
#pragma unroll
            for (int o = 0; o < 6; o++)
#pragma unroll
                for (int kk = 0; kk < 8; kk++)
                    acc[o] = dot2f(w2[o * 32 + cc * 8 + kk], hc[kk], acc[o]);
            u32 w6[8] = {w6a.x, w6a.y, w6a.z, w6a.w, w6b.x, w6b.y, w6b.z, w6b.w};
            u32 w7[8] = {w7a.x, w7a.y, w7a.z, w7a.w, w7b.x, w7b.y, w7b.z, w7b.w};
#pragma unroll
            for (int kk = 0; kk < 8; kk++) acc[6] = dot2f(w6[kk], hc[kk], acc[6]);
#pragma unroll
            for (int kk = 0; kk < 8; kk++) acc[7] = dot2f(w7[kk], hc[kk], acc[7]);
        }
#pragma unroll
        for (int o = 0; o < 8; o++) {
            acc[o] += __shfl_xor(acc[o], 1);
            acc[o] += __shfl_xor(acc[o], 2);
            acc[o] += __shfl_xor(acc[o], 4);
        }
        float r = acc[0];
#pragma unroll
        for (int o = 1; o < 8; o++)
            if (sub == o) r = acc[o];
        const float pre = xp + r;
        const float e = __expf(-2.f * fabsf(pre));
        const float th = __builtin_copysignf((1.f - e) / (1.f + e), pre);
        outb[(size_t)t * H_ + tid] = th;
        xp = xpn;
        // write h_t into the OTHER buffer (no pre-write barrier needed)
        const int wb = ((t & 1) ^ 1) << 9;  // half-index base
        const int v = tid >> 1;
        const int phys = v ^ (((v >> 5) & 7) << 2);
        reinterpret_cast<__half*>(hh)[wb + phys * 2 + (tid & 1)] = __float2half(th);
        __syncthreads();
    }
}

extern "C" void kernel_launch(void* const* d_in, const int* in_sizes, int n_in,
                              void* d_out, int out_size, void* d_ws, size_t ws_size,
                              hipStream_t stream) {
    const float* X    = (const float*)d_in[0];
    const float* Wih  = (const float*)d_in[1];
    const float* Whh  = (const float*)d_in[2];
    const float* bih  = (const float*)d_in[3];
    const float* bhh  = (const float*)d_in[4];
    float* out = (float*)d_out;
    // workspace: 98304 dwords wreg + 32768 dwords wlds = 512 KB
    u32* wreg = (u32*)d_ws;
    u32* wlds = wreg + 98304;

    prep_w<<<dim3(208), dim3(512), 0, stream>>>(Whh, wreg, wlds);
    gemm_xp<<<dim3((65536 / BM) * (H_ / BN)), dim3(256), 0, stream>>>(X, Wih, bih, bhh, out);
    rnn_scan<<<dim3(B_), dim3(512), 0, stream>>>(wreg, wlds, out);
}

// Round 2
// 2244.215 us; speedup vs baseline: 1.0092x; 1.0092x over previous
//
#include <hip/hip_runtime.h>
#include <hip/hip_fp16.h>

typedef unsigned int u32;
typedef _Float16 h2v __attribute__((ext_vector_type(2)));

#define B_ 64
#define T_ 1024
#define H_ 512
#define I_ 512

// ---------------- fp16 dot2 helper (v_dot2_f32_f16) ----------------
__device__ __forceinline__ float dot2f(u32 w, u32 h, float acc) {
#if __has_builtin(__builtin_amdgcn_fdot2)
    return __builtin_amdgcn_fdot2(__builtin_bit_cast(h2v, w),
                                  __builtin_bit_cast(h2v, h), acc, false);
#else
    __half2 a = __builtin_bit_cast(__half2, w);
    __half2 b = __builtin_bit_cast(__half2, h);
    return acc + __low2float(a) * __low2float(b) + __high2float(a) * __high2float(b);
#endif
}

// ---------------- W_hh repack: fp32 -> per-thread fp16 layout ----------------
// Scan thread tid (0..511): g = tid>>3 owns outputs j = g*8+o (o=0..7),
// sub = tid&7 owns i-slice [sub*64, sub*64+64).
// o=0..5 -> VGPR block wreg[r][tid], r = o*32+k (k = half2 index within slice)
// o=6..7 -> LDS block wlds[c][tid][q], c = (o-6)*8 + chunk, covering half2 kk=(c&7)*4+q
__global__ void prep_w(const float* __restrict__ Whh, u32* __restrict__ wreg,
                       u32* __restrict__ wlds) {
    const int tid = threadIdx.x;
    const int g = tid >> 3, sub = tid & 7;
    const int bid = blockIdx.x;
    if (bid < 192) {
        const int r = bid, o = r >> 5, k = r & 31;
        const int j = g * 8 + o, i = sub * 64 + 2 * k;
        __half2 p = __halves2half2(__float2half(Whh[j * H_ + i]),
                                   __float2half(Whh[j * H_ + i + 1]));
        wreg[r * 512 + tid] = __builtin_bit_cast(u32, p);
    } else {
        const int c = bid - 192;            // 0..15
        const int o = 6 + (c >> 3);
        const int j = g * 8 + o;
        for (int q = 0; q < 4; q++) {
            const int kk = (c & 7) * 4 + q;
            const int i = sub * 64 + 2 * kk;
            __half2 p = __halves2half2(__float2half(Whh[j * H_ + i]),
                                       __float2half(Whh[j * H_ + i + 1]));
            wlds[c * 2048 + tid * 4 + q] = __builtin_bit_cast(u32, p);
        }
    }
}

// ---------------- Phase 1: Xp = X @ W_ih^T + (b_ih + b_hh), into d_out ----------------
#define BM 128
#define BN 64
#define BK 32

__launch_bounds__(256, 3)
__global__ void gemm_xp(const float* __restrict__ X, const float* __restrict__ Wih,
                        const float* __restrict__ bih, const float* __restrict__ bhh,
                        float* __restrict__ out) {
    __shared__ float Xs[BK][BM + 4];
    __shared__ float Ws[BK][BN + 4];
    const int t = threadIdx.x;
    const int bn = blockIdx.x & 7;       // 512/64 = 8 tiles
    const int bm = blockIdx.x >> 3;      // 65536/128 = 512 tiles
    const int m0 = bm * BM, n0 = bn * BN;
    const int tm = t & 15, tn = t >> 4;  // 16 x 16 thread grid, 8x4 per thread
    float acc[8][4];
#pragma unroll
    for (int i = 0; i < 8; i++)
#pragma unroll
        for (int j = 0; j < 4; j++) acc[i][j] = 0.f;
    const int kc = t & 7, rr = t >> 3;
    for (int kt = 0; kt < I_ / BK; kt++) {
        const int k0 = kt * BK;
#pragma unroll
        for (int it = 0; it < 4; it++) {
            const int m = it * 32 + rr;
            float4 v = *(const float4*)&X[(size_t)(m0 + m) * I_ + k0 + kc * 4];
            Xs[kc * 4 + 0][m] = v.x; Xs[kc * 4 + 1][m] = v.y;
            Xs[kc * 4 + 2][m] = v.z; Xs[kc * 4 + 3][m] = v.w;
        }
#pragma unroll
        for (int it = 0; it < 2; it++) {
            const int n = it * 32 + rr;
            float4 v = *(const float4*)&Wih[(size_t)(n0 + n) * I_ + k0 + kc * 4];
            Ws[kc * 4 + 0][n] = v.x; Ws[kc * 4 + 1][n] = v.y;
            Ws[kc * 4 + 2][n] = v.z; Ws[kc * 4 + 3][n] = v.w;
        }
        __syncthreads();
#pragma unroll
        for (int k = 0; k < BK; k++) {
            float4 a0 = *(const float4*)&Xs[k][tm * 8];
            float4 a1 = *(const float4*)&Xs[k][tm * 8 + 4];
            float4 bv = *(const float4*)&Ws[k][tn * 4];
            float a[8] = {a0.x, a0.y, a0.z, a0.w, a1.x, a1.y, a1.z, a1.w};
            float bb[4] = {bv.x, bv.y, bv.z, bv.w};
#pragma unroll
            for (int mi = 0; mi < 8; mi++)
#pragma unroll
                for (int ni = 0; ni < 4; ni++)
                    acc[mi][ni] = fmaf(a[mi], bb[ni], acc[mi][ni]);
        }
        __syncthreads();
    }
    float4 b1 = *(const float4*)&bih[n0 + tn * 4];
    float4 b2 = *(const float4*)&bhh[n0 + tn * 4];
    float4 bs = {b1.x + b2.x, b1.y + b2.y, b1.z + b2.z, b1.w + b2.w};
#pragma unroll
    for (int mi = 0; mi < 8; mi++) {
        const int row = m0 + tm * 8 + mi;
        float4 st = {acc[mi][0] + bs.x, acc[mi][1] + bs.y,
                     acc[mi][2] + bs.z, acc[mi][3] + bs.w};
        *(float4*)&out[(size_t)row * H_ + n0 + tn * 4] = st;
    }
}

// ---------------- Phase 2: sequential scan, one block per batch element ----------------
// 512 threads. W_hh (fp16): 192 half2/thread in VGPRs + 64 half2/thread in LDS (128KB).
// h broadcast via XOR-swizzled half2 LDS array, ping-pong buffers -> 1 raw barrier/step.
// amdgpu_waves_per_eu(2,2): pin allocator to 2 waves/EU -> 256-VGPR budget (no spill).

#define STEP_K(k, hval)                                         \
    acc0 = dot2f(w2[0 * 32 + cc * 8 + k], (hval), acc0);        \
    acc1 = dot2f(w2[1 * 32 + cc * 8 + k], (hval), acc1);        \
    acc2 = dot2f(w2[2 * 32 + cc * 8 + k], (hval), acc2);        \
    acc3 = dot2f(w2[3 * 32 + cc * 8 + k], (hval), acc3);        \
    acc4 = dot2f(w2[4 * 32 + cc * 8 + k], (hval), acc4);        \
    acc5 = dot2f(w2[5 * 32 + cc * 8 + k], (hval), acc5);

#define RED3(a) { a += __shfl_xor(a, 1); a += __shfl_xor(a, 2); a += __shfl_xor(a, 4); }

__launch_bounds__(512)
__attribute__((amdgpu_waves_per_eu(2, 2)))
__global__ void rnn_scan(const u32* __restrict__ wreg, const u32* __restrict__ wlds_g,
                         float* __restrict__ out) {
    __shared__ u32 wl[32768];   // 128 KB
    __shared__ u32 hh[512];     // 2 x 256 half2 (ping-pong)
    const int tid = threadIdx.x;
    const int sub = tid & 7;
    u32 w2[192];
#pragma unroll
    for (int r = 0; r < 192; r++) w2[r] = wreg[r * 512 + tid];
#pragma unroll
    for (int i = 0; i < 64; i++) wl[i * 512 + tid] = wlds_g[i * 512 + tid];
    hh[tid] = 0u;               // h0 = 0 (both buffers zeroed)
    __syncthreads();
    float* p = out + (size_t)blockIdx.x * (T_ * H_) + tid;  // xp load / h store ptr
    const int xorkey = sub << 2;
    __half* hhh = reinterpret_cast<__half*>(hh);
    // per-thread write slot (invariant): v = tid>>1, phys = v ^ ((v>>5)<<2)
    const int wv = tid >> 1;
    const int wslot = (wv ^ (((wv >> 5) & 7) << 2)) * 2 + (tid & 1);
    for (int t = 0; t < T_; t++) {
        const float xp = *p;            // Xp[b,t,tid] — issued early, used ~1500cy later
        const int rb = (t & 1) << 8;    // read-buffer base (dwords)
        float acc0 = 0.f, acc1 = 0.f, acc2 = 0.f, acc3 = 0.f;
        float acc4 = 0.f, acc5 = 0.f, acc6 = 0.f, acc7 = 0.f;
#pragma unroll
        for (int cc = 0; cc < 4; cc++) {
            const int wbase = (tid << 2);
            uint4 hA = *(const uint4*)&hh[rb + ((sub * 32 + cc * 8) ^ xorkey)];
            uint4 w6a = *(const uint4*)&wl[(cc * 2 + 0) * 2048 + wbase];
            uint4 w7a = *(const uint4*)&wl[(cc * 2 + 8) * 2048 + wbase];
            STEP_K(0, hA.x); acc6 = dot2f(w6a.x, hA.x, acc6); acc7 = dot2f(w7a.x, hA.x, acc7);
            STEP_K(1, hA.y); acc6 = dot2f(w6a.y, hA.y, acc6); acc7 = dot2f(w7a.y, hA.y, acc7);
            STEP_K(2, hA.z); acc6 = dot2f(w6a.z, hA.z, acc6); acc7 = dot2f(w7a.z, hA.z, acc7);
            STEP_K(3, hA.w); acc6 = dot2f(w6a.w, hA.w, acc6); acc7 = dot2f(w7a.w, hA.w, acc7);
            uint4 hB = *(const uint4*)&hh[rb + ((sub * 32 + cc * 8 + 4) ^ xorkey)];
            uint4 w6b = *(const uint4*)&wl[(cc * 2 + 1) * 2048 + wbase];
            uint4 w7b = *(const uint4*)&wl[(cc * 2 + 9) * 2048 + wbase];
            STEP_K(4, hB.x); acc6 = dot2f(w6b.x, hB.x, acc6); acc7 = dot2f(w7b.x, hB.x, acc7);
            STEP_K(5, hB.y); acc6 = dot2f(w6b.y, hB.y, acc6); acc7 = dot2f(w7b.y, hB.y, acc7);
            STEP_K(6, hB.z); acc6 = dot2f(w6b.z, hB.z, acc6); acc7 = dot2f(w7b.z, hB.z, acc7);
            STEP_K(7, hB.w); acc6 = dot2f(w6b.w, hB.w, acc6); acc7 = dot2f(w7b.w, hB.w, acc7);
        }
        RED3(acc0); RED3(acc1); RED3(acc2); RED3(acc3);
        RED3(acc4); RED3(acc5); RED3(acc6); RED3(acc7);
        float r = acc0;
        if (sub == 1) r = acc1;
        if (sub == 2) r = acc2;
        if (sub == 3) r = acc3;
        if (sub == 4) r = acc4;
        if (sub == 5) r = acc5;
        if (sub == 6) r = acc6;
        if (sub == 7) r = acc7;
        const float pre = xp + r;
        const float e = __expf(-2.f * fabsf(pre));
        const float th = __builtin_copysignf((1.f - e) / (1.f + e), pre);
        *p = th;                        // overwrite Xp[b,t,tid] with h_t
        p += H_;
        // write h_t into the OTHER LDS buffer; raw barrier (no vmcnt drain)
        hhh[(((t & 1) ^ 1) << 9) + wslot] = __float2half(th);
        asm volatile("s_waitcnt lgkmcnt(0)" ::: "memory");
        __builtin_amdgcn_sched_barrier(0);
        __builtin_amdgcn_s_barrier();
        __builtin_amdgcn_sched_barrier(0);
    }
}

extern "C" void kernel_launch(void* const* d_in, const int* in_sizes, int n_in,
                              void* d_out, int out_size, void* d_ws, size_t ws_size,
                              hipStream_t stream) {
    const float* X    = (const float*)d_in[0];
    const float* Wih  = (const float*)d_in[1];
    const float* Whh  = (const float*)d_in[2];
    const float* bih  = (const float*)d_in[3];
    const float* bhh  = (const float*)d_in[4];
    float* out = (float*)d_out;
    // workspace: 98304 dwords wreg + 32768 dwords wlds = 512 KB
    u32* wreg = (u32*)d_ws;
    u32* wlds = wreg + 98304;

    prep_w<<<dim3(208), dim3(512), 0, stream>>>(Whh, wreg, wlds);
    gemm_xp<<<dim3((65536 / BM) * (H_ / BN)), dim3(256), 0, stream>>>(X, Wih, bih, bhh, out);
    rnn_scan<<<dim3(B_), dim3(512), 0, stream>>>(wreg, wlds, out);
}

// Round 4
// 1708.520 us; speedup vs baseline: 1.3256x; 1.3135x over previous
//
#include <hip/hip_runtime.h>
#include <hip/hip_fp16.h>

typedef unsigned int u32;
typedef _Float16 h2v __attribute__((ext_vector_type(2)));

#define B_ 64
#define T_ 1024
#define H_ 512
#define I_ 512

// ---------------- fp16 dot2 helper (v_dot2_f32_f16) ----------------
__device__ __forceinline__ float dot2f(u32 w, u32 h, float acc) {
#if __has_builtin(__builtin_amdgcn_fdot2)
    return __builtin_amdgcn_fdot2(__builtin_bit_cast(h2v, w),
                                  __builtin_bit_cast(h2v, h), acc, false);
#else
    __half2 a = __builtin_bit_cast(__half2, w);
    __half2 b = __builtin_bit_cast(__half2, h);
    return acc + __low2float(a) * __low2float(b) + __high2float(a) * __high2float(b);
#endif
}

__device__ __forceinline__ u32 pkf16(float a, float b) {
    __half2 h = __floats2half2_rn(a, b);
    return __builtin_bit_cast(u32, h);
}

// 8-lane (xor 1,2,4) reduction, pure VALU via DPP — no LDS pipe.
// xor1 = quad_perm[1,0,3,2] (0xB1); xor2 = quad_perm[2,3,0,1] (0x4E);
// xor4-equivalent = row_half_mirror (0x141): lane^7 within each 8, which after
// the first two stages holds the other quad's partial sum.
__device__ __forceinline__ float red8(float x) {
    int v = __builtin_bit_cast(int, x);
    x += __builtin_bit_cast(float, __builtin_amdgcn_update_dpp(0, v, 0xB1, 0xF, 0xF, true));
    v = __builtin_bit_cast(int, x);
    x += __builtin_bit_cast(float, __builtin_amdgcn_update_dpp(0, v, 0x4E, 0xF, 0xF, true));
    v = __builtin_bit_cast(int, x);
    x += __builtin_bit_cast(float, __builtin_amdgcn_update_dpp(0, v, 0x141, 0xF, 0xF, true));
    return x;
}

// ---------------- W_hh repack: fp32 -> per-thread fp16 layout ----------------
// Scan thread tid: g = tid>>3 owns outputs j = g*8+o (o=0..7), sub = tid&7 owns
// K-slice [sub*64, sub*64+64) (32 half2, indexed k5 = cc*8+k, cc=0..3, k=0..7).
// Registers (208 u32/thread): r<192: o = r>>5, k5 = r&31.  r=192..207: o=6, k5 = r-192 (cc<2).
// LDS (48 u32/thread, 96KB): chunks c=0..11 of [512][4] u32:
//   c<4 : o=6, cc = 2+(c>>1), half = c&1   (k5 = cc*8 + half*4 + q)
//   c>=4: o=7, c7 = c-4, cc = c7>>1, half = c7&1
__global__ void prep_w(const float* __restrict__ Whh, u32* __restrict__ wreg,
                       u32* __restrict__ wlds) {
    const int tid = threadIdx.x;
    const int g = tid >> 3, sub = tid & 7;
    const int bid = blockIdx.x;
    if (bid < 208) {
        const int r = bid;
        const int o  = (r < 192) ? (r >> 5) : 6;
        const int k5 = (r < 192) ? (r & 31) : (r - 192);
        const int j = g * 8 + o, i = sub * 64 + 2 * k5;
        wreg[r * 512 + tid] = pkf16(Whh[j * H_ + i], Whh[j * H_ + i + 1]);
    } else {
        const int c = bid - 208;            // 0..11
        int j, cc, half;
        if (c < 4) { cc = 2 + (c >> 1); half = c & 1; j = g * 8 + 6; }
        else       { int c7 = c - 4; cc = c7 >> 1; half = c7 & 1; j = g * 8 + 7; }
        for (int q = 0; q < 4; q++) {
            const int k5 = cc * 8 + half * 4 + q;
            const int i = sub * 64 + 2 * k5;
            wlds[c * 2048 + tid * 4 + q] = pkf16(Whh[j * H_ + i], Whh[j * H_ + i + 1]);
        }
    }
}

// ---------------- Phase 1: Xp = X @ W_ih^T + (b_ih + b_hh), into d_out ----------------
// fp16 staging in LDS + v_dot2_f32_f16 inner loop (halves VALU ops + LDS traffic).
// LDS spread is an XOR (bijective!): phys = m ^ (((m>>5)&1)<<2). The key depends
// only on bits>=5 and XOR touches bit 2, so each physical 4-dword quad holds the
// matching logical quad -> uint4 reads stay contiguous. (R3's additive version
// collided m=60..63 with m=64..67 -> corrupt Xs. Fixed.)
#define BM 128
#define BN 64

__launch_bounds__(256, 3)
__global__ void gemm_xp(const float* __restrict__ X, const float* __restrict__ Wih,
                        const float* __restrict__ bih, const float* __restrict__ bhh,
                        float* __restrict__ out) {
    __shared__ u32 Xs[16][BM + 4];   // half2 entries, k2-major (k2 = k/2)
    __shared__ u32 Ws[16][BN + 4];
    const int t = threadIdx.x;
    const int bn = blockIdx.x & 7;       // 512/64 = 8 tiles
    const int bm = blockIdx.x >> 3;      // 65536/128 = 512 tiles
    const int m0 = bm * BM, n0 = bn * BN;
    const int tm = t & 15, tn = t >> 4;  // 16 x 16 thread grid, 8x4 per thread
    float acc[8][4];
#pragma unroll
    for (int i = 0; i < 8; i++)
#pragma unroll
        for (int j = 0; j < 4; j++) acc[i][j] = 0.f;
    const int kc = t & 7, rr = t >> 3;
    const int key = ((tm >> 2) & 1) << 2;     // = ((m>>5)&1)<<2 for m = tm*8..tm*8+7
    for (int kt = 0; kt < 16; kt++) {
        const int k0 = kt * 32;
#pragma unroll
        for (int it = 0; it < 4; it++) {
            const int m = it * 32 + rr;
            float4 v = *(const float4*)&X[(size_t)(m0 + m) * I_ + k0 + kc * 4];
            const int mp = m ^ (((m >> 5) & 1) << 2);
            Xs[kc * 2 + 0][mp] = pkf16(v.x, v.y);
            Xs[kc * 2 + 1][mp] = pkf16(v.z, v.w);
        }
#pragma unroll
        for (int it = 0; it < 2; it++) {
            const int n = it * 32 + rr;
            float4 v = *(const float4*)&Wih[(size_t)(n0 + n) * I_ + k0 + kc * 4];
            Ws[kc * 2 + 0][n] = pkf16(v.x, v.y);
            Ws[kc * 2 + 1][n] = pkf16(v.z, v.w);
        }
        __syncthreads();
#pragma unroll
        for (int k2 = 0; k2 < 16; k2++) {
            uint4 a0 = *(const uint4*)&Xs[k2][(tm * 8) ^ key];
            uint4 a1 = *(const uint4*)&Xs[k2][(tm * 8 + 4) ^ key];
            uint4 bv = *(const uint4*)&Ws[k2][tn * 4];
            u32 aa[8] = {a0.x, a0.y, a0.z, a0.w, a1.x, a1.y, a1.z, a1.w};
            u32 bb[4] = {bv.x, bv.y, bv.z, bv.w};
#pragma unroll
            for (int mi = 0; mi < 8; mi++)
#pragma unroll
                for (int ni = 0; ni < 4; ni++)
                    acc[mi][ni] = dot2f(aa[mi], bb[ni], acc[mi][ni]);
        }
        __syncthreads();
    }
    float4 b1 = *(const float4*)&bih[n0 + tn * 4];
    float4 b2 = *(const float4*)&bhh[n0 + tn * 4];
    float4 bs = {b1.x + b2.x, b1.y + b2.y, b1.z + b2.z, b1.w + b2.w};
#pragma unroll
    for (int mi = 0; mi < 8; mi++) {
        const int row = m0 + tm * 8 + mi;
        float4 st = {acc[mi][0] + bs.x, acc[mi][1] + bs.y,
                     acc[mi][2] + bs.z, acc[mi][3] + bs.w};
        *(float4*)&out[(size_t)row * H_ + n0 + tn * 4] = st;
    }
}

// ---------------- Phase 2: sequential scan, one block per batch element ----------------
// 512 threads. W_hh fp16: 208 u32/thread in regs + 48 u32/thread in LDS (96KB).
// h broadcast via XOR-swizzled half2 LDS, ping-pong -> 1 raw barrier/step.
// Reduction over sub-lanes is pure-DPP (no LDS pipe).

#define STEP_K(k, hval)                                         \
    acc0 = dot2f(w2[0 * 32 + cc * 8 + k], (hval), acc0);        \
    acc1 = dot2f(w2[1 * 32 + cc * 8 + k], (hval), acc1);        \
    acc2 = dot2f(w2[2 * 32 + cc * 8 + k], (hval), acc2);        \
    acc3 = dot2f(w2[3 * 32 + cc * 8 + k], (hval), acc3);        \
    acc4 = dot2f(w2[4 * 32 + cc * 8 + k], (hval), acc4);        \
    acc5 = dot2f(w2[5 * 32 + cc * 8 + k], (hval), acc5);

__launch_bounds__(512)
__attribute__((amdgpu_waves_per_eu(2, 2)))
__global__ void rnn_scan(const u32* __restrict__ wreg, const u32* __restrict__ wlds_g,
                         float* __restrict__ out) {
    __shared__ u32 wl[24576];   // 96 KB: [0..8191] o=6 cc>=2, [8192..24575] o=7
    __shared__ u32 hh[512];     // 2 x 256 half2 (ping-pong)
    const int tid = threadIdx.x;
    const int sub = tid & 7;
    u32 w2[208];
#pragma unroll
    for (int r = 0; r < 208; r++) w2[r] = wreg[r * 512 + tid];
#pragma unroll
    for (int i = 0; i < 48; i++) wl[i * 512 + tid] = wlds_g[i * 512 + tid];
    hh[tid] = 0u;               // h0 = 0 (both buffers zeroed)
    __syncthreads();
    float* p = out + (size_t)blockIdx.x * (T_ * H_) + tid;  // xp load / h store ptr
    const int xorkey = sub << 2;
    __half* hhh = reinterpret_cast<__half*>(hh);
    const int wv = tid >> 1;
    const int wslot = (wv ^ (((wv >> 5) & 7) << 2)) * 2 + (tid & 1);
    const int wbase = tid << 2;
    for (int t = 0; t < T_; t++) {
        const float xp = *p;            // issued early, used ~1500cy later
        const int rb = (t & 1) << 8;    // read-buffer base (dwords)
        float acc0 = 0.f, acc1 = 0.f, acc2 = 0.f, acc3 = 0.f;
        float acc4 = 0.f, acc5 = 0.f, acc6 = 0.f, acc7 = 0.f;
#pragma unroll
        for (int cc = 0; cc < 4; cc++) {
            uint4 hA = *(const uint4*)&hh[rb + ((sub * 32 + cc * 8) ^ xorkey)];
            uint4 hB = *(const uint4*)&hh[rb + ((sub * 32 + cc * 8 + 4) ^ xorkey)];
            uint4 w7a = *(const uint4*)&wl[8192 + (cc * 2 + 0) * 2048 + wbase];
            uint4 w7b = *(const uint4*)&wl[8192 + (cc * 2 + 1) * 2048 + wbase];
            u32 h8[8]  = {hA.x, hA.y, hA.z, hA.w, hB.x, hB.y, hB.z, hB.w};
            u32 w78[8] = {w7a.x, w7a.y, w7a.z, w7a.w, w7b.x, w7b.y, w7b.z, w7b.w};
            u32 w68[8];
            if (cc < 2) {
#pragma unroll
                for (int k = 0; k < 8; k++) w68[k] = w2[192 + cc * 8 + k];
            } else {
                uint4 w6a = *(const uint4*)&wl[((cc - 2) * 2 + 0) * 2048 + wbase];
                uint4 w6b = *(const uint4*)&wl[((cc - 2) * 2 + 1) * 2048 + wbase];
                w68[0] = w6a.x; w68[1] = w6a.y; w68[2] = w6a.z; w68[3] = w6a.w;
                w68[4] = w6b.x; w68[5] = w6b.y; w68[6] = w6b.z; w68[7] = w6b.w;
            }
            STEP_K(0, h8[0]); acc6 = dot2f(w68[0], h8[0], acc6); acc7 = dot2f(w78[0], h8[0], acc7);
            STEP_K(1, h8[1]); acc6 = dot2f(w68[1], h8[1], acc6); acc7 = dot2f(w78[1], h8[1], acc7);
            STEP_K(2, h8[2]); acc6 = dot2f(w68[2], h8[2], acc6); acc7 = dot2f(w78[2], h8[2], acc7);
            STEP_K(3, h8[3]); acc6 = dot2f(w68[3], h8[3], acc6); acc7 = dot2f(w78[3], h8[3], acc7);
            STEP_K(4, h8[4]); acc6 = dot2f(w68[4], h8[4], acc6); acc7 = dot2f(w78[4], h8[4], acc7);
            STEP_K(5, h8[5]); acc6 = dot2f(w68[5], h8[5], acc6); acc7 = dot2f(w78[5], h8[5], acc7);
            STEP_K(6, h8[6]); acc6 = dot2f(w68[6], h8[6], acc6); acc7 = dot2f(w78[6], h8[6], acc7);
            STEP_K(7, h8[7]); acc6 = dot2f(w68[7], h8[7], acc6); acc7 = dot2f(w78[7], h8[7], acc7);
        }
        acc0 = red8(acc0); acc1 = red8(acc1); acc2 = red8(acc2); acc3 = red8(acc3);
        acc4 = red8(acc4); acc5 = red8(acc5); acc6 = red8(acc6); acc7 = red8(acc7);
        float r = acc0;
        if (sub == 1) r = acc1;
        if (sub == 2) r = acc2;
        if (sub == 3) r = acc3;
        if (sub == 4) r = acc4;
        if (sub == 5) r = acc5;
        if (sub == 6) r = acc6;
        if (sub == 7) r = acc7;
        const float pre = xp + r;
        const float e = __expf(-2.f * fabsf(pre));
        const float th = __builtin_copysignf((1.f - e) / (1.f + e), pre);
        *p = th;                        // overwrite Xp[b,t,tid] with h_t
        p += H_;
        hhh[(((t & 1) ^ 1) << 9) + wslot] = __float2half(th);
        asm volatile("s_waitcnt lgkmcnt(0)" ::: "memory");
        __builtin_amdgcn_sched_barrier(0);
        __builtin_amdgcn_s_barrier();
        __builtin_amdgcn_sched_barrier(0);
    }
}

extern "C" void kernel_launch(void* const* d_in, const int* in_sizes, int n_in,
                              void* d_out, int out_size, void* d_ws, size_t ws_size,
                              hipStream_t stream) {
    const float* X    = (const float*)d_in[0];
    const float* Wih  = (const float*)d_in[1];
    const float* Whh  = (const float*)d_in[2];
    const float* bih  = (const float*)d_in[3];
    const float* bhh  = (const float*)d_in[4];
    float* out = (float*)d_out;
    // workspace: 106496 dwords wreg + 24576 dwords wlds = 512 KB
    u32* wreg = (u32*)d_ws;
    u32* wlds = wreg + 106496;

    prep_w<<<dim3(220), dim3(512), 0, stream>>>(Whh, wreg, wlds);
    gemm_xp<<<dim3((65536 / BM) * (H_ / BN)), dim3(256), 0, stream>>>(X, Wih, bih, bhh, out);
    rnn_scan<<<dim3(B_), dim3(512), 0, stream>>>(wreg, wlds, out);
}